// Round 13
// baseline (303.839 us; speedup 1.0000x reference)
//
#include <hip/hip_runtime.h>
#include <hip/hip_bf16.h>

#define BS    128
#define NCIN  64
#define NCOUT 64
#define LLEN  8192
#define NK    3
#define NR    8
#define NEMB  256
#define NHID  256
#define WPS   (NCOUT * NCIN * NK)   // 12288 weights per sample
#define NT    512                   // l-positions per conv tile/block (2 KB chunks)

typedef __attribute__((ext_vector_type(4)))  float  f32x4;
typedef __attribute__((ext_vector_type(16))) float  f32x16;
typedef __attribute__((ext_vector_type(8)))  __bf16 bf16x8;

// Static device scratch (fully rewritten every call).
__device__ float  g_h[2][NHID * BS]; // hidden, TRANSPOSED: [branch][k][s]
__device__ float  g_A[BS * 512];     // A factors [b][ci*8+r]
__device__ float  g_B[BS * 1536];    // B factors [b][r*192+co*3+k]
__device__ __bf16 g_Wb[BS * WPS];    // W_eff bf16 [b][k*4096+co*64+ci]

// ---------------------------------------------------------------------------
// Kernel 1a: hidden layer, weight-uniform GEMM style. 8 blocks = (branch, och).
// Thread: lane = sample, 32 outputs in registers. No LDS, no barriers.
// ---------------------------------------------------------------------------
__global__ __launch_bounds__(256) void mlp_hid(
    const float* __restrict__ a_emb, const float* __restrict__ b_emb,
    const float* __restrict__ A_w1, const float* __restrict__ A_b1,
    const float* __restrict__ A_g,  const float* __restrict__ A_beta,
    const float* __restrict__ B_w1, const float* __restrict__ B_b1,
    const float* __restrict__ B_g,  const float* __restrict__ B_beta)
{
    const int t      = threadIdx.x;
    const int branch = blockIdx.x >> 2;
    const int och    = blockIdx.x & 3;
    const int s      = (t & 63) + (t >> 7) * 64;                 // sample 0..127
    const int og     = __builtin_amdgcn_readfirstlane((t >> 6) & 1);
    const int o0     = och * 64 + og * 32;

    const float* emb = (branch ? b_emb : a_emb) + (size_t)s * NEMB;
    const float* w1  = (branch ? B_w1 : A_w1) + (size_t)o0 * NEMB;
    const float* b1  = (branch ? B_b1 : A_b1) + o0;
    const float* gg  = (branch ? B_g  : A_g)  + o0;
    const float* bt  = (branch ? B_beta : A_beta) + o0;
    float* hout = g_h[branch];

    float acc[32];
    #pragma unroll
    for (int i = 0; i < 32; ++i) acc[i] = b1[i];

    for (int e = 0; e < NEMB / 4; ++e) {
        f32x4 em = *(const f32x4*)(emb + e * 4);
        #pragma unroll
        for (int i = 0; i < 32; ++i) {
            f32x4 w = *(const f32x4*)(w1 + (size_t)i * NEMB + e * 4);  // uniform -> scalar
            acc[i] += w[0]*em[0] + w[1]*em[1] + w[2]*em[2] + w[3]*em[3];
        }
    }
    const float bnc = 1.0f / sqrtf(1.0f + 1e-5f);
    #pragma unroll
    for (int i = 0; i < 32; ++i) {
        float h = acc[i] * (gg[i] * bnc) + bt[i];
        h = 0.5f * h * (1.0f + erff(h * 0.70710678118654752f));
        hout[(size_t)(o0 + i) * BS + s] = h;   // [k][s]: 256B contiguous per instr
    }
}

// ---------------------------------------------------------------------------
// Kernel 1b: output layers. 32 blocks: 0..7 -> A (512 outs), 8..31 -> B (1536).
// ---------------------------------------------------------------------------
__global__ __launch_bounds__(256) void mlp_out(
    const float* __restrict__ A_w2, const float* __restrict__ A_b2,
    const float* __restrict__ B_w2, const float* __restrict__ B_b2)
{
    const int blk    = blockIdx.x;
    const int branch = (blk >= 8) ? 1 : 0;
    const int chunk  = branch ? (blk - 8) : blk;
    const int t   = threadIdx.x;
    const int s   = (t & 63) + (t >> 7) * 64;
    const int og  = __builtin_amdgcn_readfirstlane((t >> 6) & 1);
    const int o0  = chunk * 64 + og * 32;

    const float* w2 = (branch ? B_w2 : A_w2) + (size_t)o0 * NHID;
    const float* b2 = (branch ? B_b2 : A_b2) + o0;
    const float* h  = g_h[branch];
    float* outp = branch ? g_B : g_A;
    const int ostr = branch ? 1536 : 512;

    float acc[32];
    #pragma unroll
    for (int i = 0; i < 32; ++i) acc[i] = b2[i];

    for (int e = 0; e < NHID / 4; ++e) {
        const float h0 = h[(size_t)(e * 4 + 0) * BS + s];   // coalesced 256B reads
        const float h1 = h[(size_t)(e * 4 + 1) * BS + s];
        const float h2 = h[(size_t)(e * 4 + 2) * BS + s];
        const float h3 = h[(size_t)(e * 4 + 3) * BS + s];
        #pragma unroll
        for (int i = 0; i < 32; ++i) {
            f32x4 w = *(const f32x4*)(w2 + (size_t)i * NHID + e * 4);  // uniform
            acc[i] += w[0]*h0 + w[1]*h1 + w[2]*h2 + w[3]*h3;
        }
    }
    float* op = outp + (size_t)s * ostr + o0;
    #pragma unroll
    for (int i = 0; i < 32; i += 4) {
        f32x4 v = { acc[i], acc[i+1], acc[i+2], acc[i+3] };
        *(f32x4*)(op + i) = v;    // 128B contiguous per thread
    }
}

// ---------------------------------------------------------------------------
// Kernel 2: assemble W_eff = base_w + A·B  (bf16, [b][k*4096+co*64+ci]).
// ---------------------------------------------------------------------------
__global__ __launch_bounds__(256) void assemble_kernel(const float* __restrict__ base_w)
{
    const int b  = blockIdx.x >> 2;
    const int q  = blockIdx.x & 3;
    const int t  = threadIdx.x;
    const int ci = t & 63;

    float Ar[NR];
    const f32x4* Ap = (const f32x4*)(g_A + (size_t)b * 512 + ci * NR);
    f32x4 a0 = Ap[0], a1 = Ap[1];
    Ar[0]=a0[0]; Ar[1]=a0[1]; Ar[2]=a0[2]; Ar[3]=a0[3];
    Ar[4]=a1[0]; Ar[5]=a1[1]; Ar[6]=a1[2]; Ar[7]=a1[3];

    const float* Bp = g_B + (size_t)b * 1536;
    for (int i = 0; i < 12; ++i) {
        const int w  = q * 3072 + i * 256 + t;
        const int k  = w >> 12;
        const int co = (w >> 6) & 63;
        float v = base_w[(size_t)(co * 64 + ci) * 3 + k];
        #pragma unroll
        for (int r = 0; r < NR; ++r) v += Ar[r] * Bp[r * 192 + co * 3 + k];
        g_Wb[(size_t)b * WPS + w] = (__bf16)v;
    }
}

// ---------------------------------------------------------------------------
// Kernel 3: conv as MFMA GEMM, NT=512 tiles (R11 verbatim — best measured).
// 2048 blocks = (b, 512-l tile), XCD-swizzled. LDS 65.8 KB -> 2 blocks/CU.
// ---------------------------------------------------------------------------
__global__ __launch_bounds__(256, 2) void conv_kernel(
    const float* __restrict__ X, const float* __restrict__ base_b,
    float* __restrict__ out)
{
    __shared__ __align__(16) __bf16 xt[(NT + 2) * 64];   // 65792 B

    const int swz  = (blockIdx.x & 7) * 256 + (blockIdx.x >> 3);
    const int b    = swz >> 4;            // 16 tiles per sample
    const int tile = swz & 15;
    const int l0   = tile * NT;

    const int t     = threadIdx.x;
    const int lane  = t & 63;
    const int wave  = t >> 6;
    const int l31   = lane & 31;
    const int khalf = lane >> 5;
    const int wco   = wave >> 1;
    const int wl    = wave & 1;
    const int lb    = t & 63;
    const int ch    = t >> 6;

    const float* xbase = X + (size_t)b * NCIN * LLEN;

    #pragma unroll
    for (int pass = 0; pass < 2; ++pass) {
        const int och = ch + pass * 4;
        f32x4 v[8][2];
        const float* xb = xbase + l0 + lb * 8;
        #pragma unroll
        for (int c = 0; c < 8; ++c) {
            const float* xr = xb + (size_t)(och * 8 + c) * LLEN;
            v[c][0] = *(const f32x4*)(xr);
            v[c][1] = *(const f32x4*)(xr + 4);
        }
        #pragma unroll
        for (int j = 0; j < 8; ++j) {
            const int lp = lb * 8 + j + 1;
            bf16x8 w;
            #pragma unroll
            for (int c = 0; c < 8; ++c) w[c] = (__bf16)v[c][j >> 2][j & 3];
            const int blk = och ^ (lp & 7) ^ ((lp >> 3) & 7);
            *(bf16x8*)(xt + lp * 64 + blk * 8) = w;
        }
    }
    if (t < 128) {  // halo columns (pad = 1)
        const int ci    = t & 63;
        const int right = t >> 6;
        const int gl    = right ? (l0 + NT) : (l0 - 1);
        const int lp    = right ? (NT + 1) : 0;
        const float hv  = (gl >= 0 && gl < LLEN) ? xbase[(size_t)ci * LLEN + gl] : 0.0f;
        const int blk   = (ci >> 3) ^ (lp & 7) ^ ((lp >> 3) & 7);
        xt[lp * 64 + blk * 8 + (ci & 7)] = (__bf16)hv;
    }
    __syncthreads();

    bf16x8 af[3][4];
    {
        const __bf16* wb = g_Wb + (size_t)b * WPS + (wco * 32 + l31) * 64 + khalf * 8;
        #pragma unroll
        for (int tap = 0; tap < 3; ++tap)
            #pragma unroll
            for (int c16 = 0; c16 < 4; ++c16)
                af[tap][c16] = *(const bf16x8*)(wb + tap * 4096 + c16 * 16);
    }

    f32x16 acc[8] = {};
    #pragma unroll
    for (int tap = 0; tap < 3; ++tap)
        #pragma unroll
        for (int c16 = 0; c16 < 4; ++c16)
            #pragma unroll
            for (int n = 0; n < 8; ++n) {
                const int R   = wl * 256 + n * 32 + l31 + tap;
                const int blk = (c16 * 2 + khalf) ^ (R & 7) ^ ((R >> 3) & 7);
                bf16x8 bfr = *(const bf16x8*)(xt + R * 64 + blk * 8);
                acc[n] = __builtin_amdgcn_mfma_f32_32x32x16_bf16(af[tap][c16], bfr, acc[n], 0, 0, 0);
            }

    #pragma unroll
    for (int reg = 0; reg < 16; ++reg) {
        const int col = (reg & 3) + 8 * (reg >> 2) + 4 * khalf;
        const int co  = wco * 32 + col;
        const float bb = base_b[co];
        float* op = out + (size_t)(b * NCOUT + co) * LLEN + l0 + wl * 256 + l31;
        #pragma unroll
        for (int n = 0; n < 8; ++n)
            op[n * 32] = acc[n][reg] + bb;
    }
}

// ---------------------------------------------------------------------------
extern "C" void kernel_launch(void* const* d_in, const int* in_sizes, int n_in,
                              void* d_out, int out_size, void* d_ws, size_t ws_size,
                              hipStream_t stream)
{
    const float* X      = (const float*)d_in[0];
    const float* a_emb  = (const float*)d_in[1];
    const float* b_emb  = (const float*)d_in[2];
    const float* A_w1   = (const float*)d_in[3];
    const float* A_b1   = (const float*)d_in[4];
    const float* A_g    = (const float*)d_in[5];
    const float* A_beta = (const float*)d_in[6];
    const float* A_w2   = (const float*)d_in[7];
    const float* A_b2   = (const float*)d_in[8];
    const float* B_w1   = (const float*)d_in[9];
    const float* B_b1   = (const float*)d_in[10];
    const float* B_g    = (const float*)d_in[11];
    const float* B_beta = (const float*)d_in[12];
    const float* B_w2   = (const float*)d_in[13];
    const float* B_b2   = (const float*)d_in[14];
    const float* base_w = (const float*)d_in[15];
    const float* base_b = (const float*)d_in[16];

    float* out = (float*)d_out;   // reference output dtype is float32

    mlp_hid<<<8, 256, 0, stream>>>(a_emb, b_emb,
        A_w1, A_b1, A_g, A_beta, B_w1, B_b1, B_g, B_beta);

    mlp_out<<<32, 256, 0, stream>>>(A_w2, A_b2, B_w2, B_b2);

    assemble_kernel<<<4 * BS, 256, 0, stream>>>(base_w);

    conv_kernel<<<2048, 256, 0, stream>>>(X, base_b, out);
}

// Round 14
// 192.267 us; speedup vs baseline: 1.5803x; 1.5803x over previous
//
#include <hip/hip_runtime.h>
#include <hip/hip_bf16.h>

#define BS    128
#define NCIN  64
#define NCOUT 64
#define LLEN  8192
#define NK    3
#define NR    8
#define NEMB  256
#define NHID  256
#define WPS   (NCOUT * NCIN * NK)   // 12288 weights per sample
#define NT    512                   // l-positions per conv tile/block (2 KB chunks)

typedef __attribute__((ext_vector_type(4)))  float  f32x4;
typedef __attribute__((ext_vector_type(16))) float  f32x16;
typedef __attribute__((ext_vector_type(8)))  __bf16 bf16x8;

// Static device scratch (fully rewritten every call).
__device__ float  g_A[BS * 512];    // A factors [b][ci*8+r]
__device__ float  g_B[BS * 1536];   // B factors [b][r*192+co*3+k]
__device__ __bf16 g_Wb[BS * WPS];   // W_eff bf16 [b][k*4096+co*64+ci]

// ---------------------------------------------------------------------------
// Kernel 1: MLP branches (hidden + outputs fused). 256 blocks = (branch, sample).
// (R11 verbatim — R13's restructure regressed; grid parallelism dominates.)
// ---------------------------------------------------------------------------
__global__ __launch_bounds__(256) void mlp_kernel(
    const float* __restrict__ a_emb, const float* __restrict__ b_emb,
    const float* __restrict__ A_w1, const float* __restrict__ A_b1,
    const float* __restrict__ A_g,  const float* __restrict__ A_beta,
    const float* __restrict__ A_w2, const float* __restrict__ A_b2,
    const float* __restrict__ B_w1, const float* __restrict__ B_b1,
    const float* __restrict__ B_g,  const float* __restrict__ B_beta,
    const float* __restrict__ B_w2, const float* __restrict__ B_b2)
{
    __shared__ __align__(16) float emb_s[NEMB];
    __shared__ __align__(16) float h_s[NHID];

    const int t      = threadIdx.x;
    const int branch = blockIdx.x >> 7;
    const int b      = blockIdx.x & 127;

    const float* emb  = (branch ? b_emb : a_emb) + (size_t)b * NEMB;
    const float* w1   = branch ? B_w1 : A_w1;
    const float* b1   = branch ? B_b1 : A_b1;
    const float* gg   = branch ? B_g  : A_g;
    const float* bt   = branch ? B_beta : A_beta;
    const float* w2   = branch ? B_w2 : A_w2;
    const float* b2   = branch ? B_b2 : A_b2;
    float* outp       = (branch ? g_B : g_A) + (size_t)b * (branch ? 1536 : 512);
    const int nloops  = branch ? 6 : 2;

    emb_s[t] = emb[t];
    __syncthreads();

    // hidden: Linear + BN(eval, mean=0 var=1) + exact GELU
    {
        float acc = b1[t];
        const f32x4* wr = (const f32x4*)(w1 + (size_t)t * NEMB);
        const f32x4* es = (const f32x4*)emb_s;
        for (int e = 0; e < NEMB / 4; ++e) {
            f32x4 w = wr[e], a = es[e];
            acc += w[0]*a[0] + w[1]*a[1] + w[2]*a[2] + w[3]*a[3];
        }
        float h = acc * (gg[t] * (1.0f / sqrtf(1.0f + 1e-5f))) + bt[t];
        h = 0.5f * h * (1.0f + erff(h * 0.70710678118654752f));
        h_s[t] = h;
    }
    __syncthreads();

    // outputs
    for (int oo = 0; oo < nloops; ++oo) {
        const int o = oo * 256 + t;
        float acc = b2[o];
        const f32x4* wr = (const f32x4*)(w2 + (size_t)o * NHID);
        const f32x4* hs = (const f32x4*)h_s;
        for (int e = 0; e < NHID / 4; ++e) {
            f32x4 w = wr[e], h = hs[e];
            acc += w[0]*h[0] + w[1]*h[1] + w[2]*h[2] + w[3]*h[3];
        }
        outp[o] = acc;
    }
}

// ---------------------------------------------------------------------------
// Kernel 2: assemble W_eff = base_w + A·B  (bf16, [b][k*4096+co*64+ci]).
// ---------------------------------------------------------------------------
__global__ __launch_bounds__(256) void assemble_kernel(const float* __restrict__ base_w)
{
    const int b  = blockIdx.x >> 2;
    const int q  = blockIdx.x & 3;
    const int t  = threadIdx.x;
    const int ci = t & 63;

    float Ar[NR];
    const f32x4* Ap = (const f32x4*)(g_A + (size_t)b * 512 + ci * NR);
    f32x4 a0 = Ap[0], a1 = Ap[1];
    Ar[0]=a0[0]; Ar[1]=a0[1]; Ar[2]=a0[2]; Ar[3]=a0[3];
    Ar[4]=a1[0]; Ar[5]=a1[1]; Ar[6]=a1[2]; Ar[7]=a1[3];

    const float* Bp = g_B + (size_t)b * 1536;
    for (int i = 0; i < 12; ++i) {
        const int w  = q * 3072 + i * 256 + t;
        const int k  = w >> 12;
        const int co = (w >> 6) & 63;
        float v = base_w[(size_t)(co * 64 + ci) * 3 + k];
        #pragma unroll
        for (int r = 0; r < NR; ++r) v += Ar[r] * Bp[r * 192 + co * 3 + k];
        g_Wb[(size_t)b * WPS + w] = (__bf16)v;
    }
}

// ---------------------------------------------------------------------------
// Kernel 3: conv as MFMA GEMM, NT=512 (R11 structure) + NON-TEMPORAL X loads
// and out stores (streaming: X read-once, out write-once-never-read).
// 2048 blocks = (b, 512-l tile), XCD-swizzled. LDS 65.8 KB -> 2 blocks/CU.
// ---------------------------------------------------------------------------
__global__ __launch_bounds__(256, 2) void conv_kernel(
    const float* __restrict__ X, const float* __restrict__ base_b,
    float* __restrict__ out)
{
    __shared__ __align__(16) __bf16 xt[(NT + 2) * 64];   // 65792 B

    const int swz  = (blockIdx.x & 7) * 256 + (blockIdx.x >> 3);
    const int b    = swz >> 4;            // 16 tiles per sample
    const int tile = swz & 15;
    const int l0   = tile * NT;

    const int t     = threadIdx.x;
    const int lane  = t & 63;
    const int wave  = t >> 6;
    const int l31   = lane & 31;
    const int khalf = lane >> 5;
    const int wco   = wave >> 1;
    const int wl    = wave & 1;
    const int lb    = t & 63;
    const int ch    = t >> 6;

    const float* xbase = X + (size_t)b * NCIN * LLEN;

    #pragma unroll
    for (int pass = 0; pass < 2; ++pass) {
        const int och = ch + pass * 4;
        f32x4 v[8][2];
        const float* xb = xbase + l0 + lb * 8;
        #pragma unroll
        for (int c = 0; c < 8; ++c) {
            const float* xr = xb + (size_t)(och * 8 + c) * LLEN;
            v[c][0] = __builtin_nontemporal_load((const f32x4*)(xr));
            v[c][1] = __builtin_nontemporal_load((const f32x4*)(xr + 4));
        }
        #pragma unroll
        for (int j = 0; j < 8; ++j) {
            const int lp = lb * 8 + j + 1;
            bf16x8 w;
            #pragma unroll
            for (int c = 0; c < 8; ++c) w[c] = (__bf16)v[c][j >> 2][j & 3];
            const int blk = och ^ (lp & 7) ^ ((lp >> 3) & 7);
            *(bf16x8*)(xt + lp * 64 + blk * 8) = w;
        }
    }
    if (t < 128) {  // halo columns (pad = 1)
        const int ci    = t & 63;
        const int right = t >> 6;
        const int gl    = right ? (l0 + NT) : (l0 - 1);
        const int lp    = right ? (NT + 1) : 0;
        const float hv  = (gl >= 0 && gl < LLEN) ? xbase[(size_t)ci * LLEN + gl] : 0.0f;
        const int blk   = (ci >> 3) ^ (lp & 7) ^ ((lp >> 3) & 7);
        xt[lp * 64 + blk * 8 + (ci & 7)] = (__bf16)hv;
    }
    __syncthreads();

    bf16x8 af[3][4];
    {
        const __bf16* wb = g_Wb + (size_t)b * WPS + (wco * 32 + l31) * 64 + khalf * 8;
        #pragma unroll
        for (int tap = 0; tap < 3; ++tap)
            #pragma unroll
            for (int c16 = 0; c16 < 4; ++c16)
                af[tap][c16] = *(const bf16x8*)(wb + tap * 4096 + c16 * 16);
    }

    f32x16 acc[8] = {};
    #pragma unroll
    for (int tap = 0; tap < 3; ++tap)
        #pragma unroll
        for (int c16 = 0; c16 < 4; ++c16)
            #pragma unroll
            for (int n = 0; n < 8; ++n) {
                const int R   = wl * 256 + n * 32 + l31 + tap;
                const int blk = (c16 * 2 + khalf) ^ (R & 7) ^ ((R >> 3) & 7);
                bf16x8 bfr = *(const bf16x8*)(xt + R * 64 + blk * 8);
                acc[n] = __builtin_amdgcn_mfma_f32_32x32x16_bf16(af[tap][c16], bfr, acc[n], 0, 0, 0);
            }

    #pragma unroll
    for (int reg = 0; reg < 16; ++reg) {
        const int col = (reg & 3) + 8 * (reg >> 2) + 4 * khalf;
        const int co  = wco * 32 + col;
        const float bb = base_b[co];
        float* op = out + (size_t)(b * NCOUT + co) * LLEN + l0 + wl * 256 + l31;
        #pragma unroll
        for (int n = 0; n < 8; ++n)
            __builtin_nontemporal_store(acc[n][reg] + bb, op + n * 32);
    }
}

// ---------------------------------------------------------------------------
extern "C" void kernel_launch(void* const* d_in, const int* in_sizes, int n_in,
                              void* d_out, int out_size, void* d_ws, size_t ws_size,
                              hipStream_t stream)
{
    const float* X      = (const float*)d_in[0];
    const float* a_emb  = (const float*)d_in[1];
    const float* b_emb  = (const float*)d_in[2];
    const float* A_w1   = (const float*)d_in[3];
    const float* A_b1   = (const float*)d_in[4];
    const float* A_g    = (const float*)d_in[5];
    const float* A_beta = (const float*)d_in[6];
    const float* A_w2   = (const float*)d_in[7];
    const float* A_b2   = (const float*)d_in[8];
    const float* B_w1   = (const float*)d_in[9];
    const float* B_b1   = (const float*)d_in[10];
    const float* B_g    = (const float*)d_in[11];
    const float* B_beta = (const float*)d_in[12];
    const float* B_w2   = (const float*)d_in[13];
    const float* B_b2   = (const float*)d_in[14];
    const float* base_w = (const float*)d_in[15];
    const float* base_b = (const float*)d_in[16];

    float* out = (float*)d_out;   // reference output dtype is float32

    mlp_kernel<<<2 * BS, 256, 0, stream>>>(a_emb, b_emb,
        A_w1, A_b1, A_g, A_beta, A_w2, A_b2,
        B_w1, B_b1, B_g, B_beta, B_w2, B_b2);

    assemble_kernel<<<4 * BS, 256, 0, stream>>>(base_w);

    conv_kernel<<<2048, 256, 0, stream>>>(X, base_b, out);
}

// Round 15
// 186.478 us; speedup vs baseline: 1.6294x; 1.0310x over previous
//
#include <hip/hip_runtime.h>
#include <hip/hip_bf16.h>

#define BS    128
#define NCIN  64
#define NCOUT 64
#define LLEN  8192
#define NK    3
#define NR    8
#define NEMB  256
#define NHID  256
#define WPS   (NCOUT * NCIN * NK)   // 12288 weights per sample
#define NT    1024                  // l-positions per conv block (4 KB chunks/row)

typedef __attribute__((ext_vector_type(4)))  float  f32x4;
typedef __attribute__((ext_vector_type(16))) float  f32x16;
typedef __attribute__((ext_vector_type(8)))  __bf16 bf16x8;

// Static device scratch (fully rewritten every call).
__device__ float  g_A[BS * 512];    // A factors [b][ci*8+r]
__device__ float  g_B[BS * 1536];   // B factors [b][r*192+co*3+k]
__device__ __bf16 g_Wb[BS * WPS];   // W_eff bf16 [b][k*4096+co*64+ci]

// ---------------------------------------------------------------------------
// Kernel 1: MLP branches (hidden + outputs fused). 256 blocks = (branch, sample).
// (R11 verbatim.)
// ---------------------------------------------------------------------------
__global__ __launch_bounds__(256) void mlp_kernel(
    const float* __restrict__ a_emb, const float* __restrict__ b_emb,
    const float* __restrict__ A_w1, const float* __restrict__ A_b1,
    const float* __restrict__ A_g,  const float* __restrict__ A_beta,
    const float* __restrict__ A_w2, const float* __restrict__ A_b2,
    const float* __restrict__ B_w1, const float* __restrict__ B_b1,
    const float* __restrict__ B_g,  const float* __restrict__ B_beta,
    const float* __restrict__ B_w2, const float* __restrict__ B_b2)
{
    __shared__ __align__(16) float emb_s[NEMB];
    __shared__ __align__(16) float h_s[NHID];

    const int t      = threadIdx.x;
    const int branch = blockIdx.x >> 7;
    const int b      = blockIdx.x & 127;

    const float* emb  = (branch ? b_emb : a_emb) + (size_t)b * NEMB;
    const float* w1   = branch ? B_w1 : A_w1;
    const float* b1   = branch ? B_b1 : A_b1;
    const float* gg   = branch ? B_g  : A_g;
    const float* bt   = branch ? B_beta : A_beta;
    const float* w2   = branch ? B_w2 : A_w2;
    const float* b2   = branch ? B_b2 : A_b2;
    float* outp       = (branch ? g_B : g_A) + (size_t)b * (branch ? 1536 : 512);
    const int nloops  = branch ? 6 : 2;

    emb_s[t] = emb[t];
    __syncthreads();

    // hidden: Linear + BN(eval, mean=0 var=1) + exact GELU
    {
        float acc = b1[t];
        const f32x4* wr = (const f32x4*)(w1 + (size_t)t * NEMB);
        const f32x4* es = (const f32x4*)emb_s;
        for (int e = 0; e < NEMB / 4; ++e) {
            f32x4 w = wr[e], a = es[e];
            acc += w[0]*a[0] + w[1]*a[1] + w[2]*a[2] + w[3]*a[3];
        }
        float h = acc * (gg[t] * (1.0f / sqrtf(1.0f + 1e-5f))) + bt[t];
        h = 0.5f * h * (1.0f + erff(h * 0.70710678118654752f));
        h_s[t] = h;
    }
    __syncthreads();

    // outputs
    for (int oo = 0; oo < nloops; ++oo) {
        const int o = oo * 256 + t;
        float acc = b2[o];
        const f32x4* wr = (const f32x4*)(w2 + (size_t)o * NHID);
        const f32x4* hs = (const f32x4*)h_s;
        for (int e = 0; e < NHID / 4; ++e) {
            f32x4 w = wr[e], h = hs[e];
            acc += w[0]*h[0] + w[1]*h[1] + w[2]*h[2] + w[3]*h[3];
        }
        outp[o] = acc;
    }
}

// ---------------------------------------------------------------------------
// Kernel 2: assemble W_eff = base_w + A·B  (bf16, [b][k*4096+co*64+ci]).
// (R11 verbatim.)
// ---------------------------------------------------------------------------
__global__ __launch_bounds__(256) void assemble_kernel(const float* __restrict__ base_w)
{
    const int b  = blockIdx.x >> 2;
    const int q  = blockIdx.x & 3;
    const int t  = threadIdx.x;
    const int ci = t & 63;

    float Ar[NR];
    const f32x4* Ap = (const f32x4*)(g_A + (size_t)b * 512 + ci * NR);
    f32x4 a0 = Ap[0], a1 = Ap[1];
    Ar[0]=a0[0]; Ar[1]=a0[1]; Ar[2]=a0[2]; Ar[3]=a0[3];
    Ar[4]=a1[0]; Ar[5]=a1[1]; Ar[6]=a1[2]; Ar[7]=a1[3];

    const float* Bp = g_B + (size_t)b * 1536;
    for (int i = 0; i < 12; ++i) {
        const int w  = q * 3072 + i * 256 + t;
        const int k  = w >> 12;
        const int co = (w >> 6) & 63;
        float v = base_w[(size_t)(co * 64 + ci) * 3 + k];
        #pragma unroll
        for (int r = 0; r < NR; ++r) v += Ar[r] * Bp[r * 192 + co * 3 + k];
        g_Wb[(size_t)b * WPS + w] = (__bf16)v;
    }
}

// ---------------------------------------------------------------------------
// Kernel 3: conv as MFMA GEMM, NT=1024 (4 KB per-row bursts). 1024 blocks =
// (b, 1024-l tile), XCD-swizzled, 1 block/CU (131.3 KB LDS), no tail.
// Staging: per row, 4 back-to-back 1KB lane-contiguous loads (4 KB burst);
// writes are uniform 8-phase (minimum) across banks.
// LDS: [lp][ci] bf16, lp 0..1025, blk-swizzle (ci>>3)^(lp&7)^((lp>>3)&7).
// Per wave: 32 co (wco) x 512 l (wl); 192 MFMA 32x32x16, acc 256 VGPR (1 wave/SIMD).
// ---------------------------------------------------------------------------
__global__ __launch_bounds__(256, 1) void conv_kernel(
    const float* __restrict__ X, const float* __restrict__ base_b,
    float* __restrict__ out)
{
    __shared__ __align__(16) __bf16 xt[(NT + 2) * 64];   // 131,328 B

    // bijective XCD swizzle: XCD x owns 128 consecutive swz (16 b x 8 tiles)
    const int swz = (blockIdx.x & 7) * 128 + (blockIdx.x >> 3);
    const int b   = swz >> 3;
    const int l0  = (swz & 7) * NT;

    const int t     = threadIdx.x;
    const int lane  = t & 63;
    const int wave  = t >> 6;
    const int l31   = lane & 31;
    const int khalf = lane >> 5;
    const int wco   = wave >> 1;          // which 32 co
    const int wl    = wave & 1;           // which 512 l
    const int ch    = wave;               // staging: base ci-octet (0..3)

    const float* xbase = X + (size_t)b * NCIN * LLEN;

    // ---- stage X tile: per row, 4x 1KB contiguous loads = 4KB burst ----
    #pragma unroll
    for (int pass = 0; pass < 2; ++pass) {
        const int och = ch + pass * 4;    // ci-octet 0..7
        f32x4 v[8][4];
        const float* rb = xbase + (size_t)(och * 8) * LLEN + l0 + lane * 4;
        #pragma unroll
        for (int c = 0; c < 8; ++c) {
            const float* xr = rb + (size_t)c * LLEN;
            #pragma unroll
            for (int k = 0; k < 4; ++k)
                v[c][k] = *(const f32x4*)(xr + k * 256);
        }
        #pragma unroll
        for (int k = 0; k < 4; ++k)
            #pragma unroll
            for (int e = 0; e < 4; ++e) {
                const int lp = k * 256 + lane * 4 + e + 1;
                bf16x8 w;
                #pragma unroll
                for (int c = 0; c < 8; ++c) w[c] = (__bf16)v[c][k][e];
                const int blk = och ^ (lp & 7) ^ ((lp >> 3) & 7);
                *(bf16x8*)(xt + lp * 64 + blk * 8) = w;
            }
    }
    if (t < 128) {  // halo columns (pad = 1)
        const int ci    = t & 63;
        const int right = t >> 6;
        const int gl    = right ? (l0 + NT) : (l0 - 1);
        const int lp    = right ? (NT + 1) : 0;
        const float hv  = (gl >= 0 && gl < LLEN) ? xbase[(size_t)ci * LLEN + gl] : 0.0f;
        const int blk   = (ci >> 3) ^ (lp & 7) ^ ((lp >> 3) & 7);
        xt[lp * 64 + blk * 8 + (ci & 7)] = (__bf16)hv;
    }
    __syncthreads();

    // ---- W fragments ----
    bf16x8 af[3][4];
    {
        const __bf16* wb = g_Wb + (size_t)b * WPS + (wco * 32 + l31) * 64 + khalf * 8;
        #pragma unroll
        for (int tap = 0; tap < 3; ++tap)
            #pragma unroll
            for (int c16 = 0; c16 < 4; ++c16)
                af[tap][c16] = *(const bf16x8*)(wb + tap * 4096 + c16 * 16);
    }

    // ---- MFMA: 16 l-subtiles x (3 taps x 4 ci16) ----
    f32x16 acc[16] = {};
    #pragma unroll
    for (int tap = 0; tap < 3; ++tap)
        #pragma unroll
        for (int c16 = 0; c16 < 4; ++c16)
            #pragma unroll
            for (int n = 0; n < 16; ++n) {
                const int R   = wl * 512 + n * 32 + l31 + tap;
                const int blk = (c16 * 2 + khalf) ^ (R & 7) ^ ((R >> 3) & 7);
                bf16x8 bfr = *(const bf16x8*)(xt + R * 64 + blk * 8);
                acc[n] = __builtin_amdgcn_mfma_f32_32x32x16_bf16(af[tap][c16], bfr, acc[n], 0, 0, 0);
            }

    // ---- epilogue: + base_b, direct stores (2 x 128 B full lines per instr) ----
    #pragma unroll
    for (int reg = 0; reg < 16; ++reg) {
        const int col = (reg & 3) + 8 * (reg >> 2) + 4 * khalf;  // co_local
        const int co  = wco * 32 + col;
        const float bb = base_b[co];
        float* op = out + (size_t)(b * NCOUT + co) * LLEN + l0 + wl * 512 + l31;
        #pragma unroll
        for (int n = 0; n < 16; ++n)
            op[n * 32] = acc[n][reg] + bb;
    }
}

// ---------------------------------------------------------------------------
extern "C" void kernel_launch(void* const* d_in, const int* in_sizes, int n_in,
                              void* d_out, int out_size, void* d_ws, size_t ws_size,
                              hipStream_t stream)
{
    const float* X      = (const float*)d_in[0];
    const float* a_emb  = (const float*)d_in[1];
    const float* b_emb  = (const float*)d_in[2];
    const float* A_w1   = (const float*)d_in[3];
    const float* A_b1   = (const float*)d_in[4];
    const float* A_g    = (const float*)d_in[5];
    const float* A_beta = (const float*)d_in[6];
    const float* A_w2   = (const float*)d_in[7];
    const float* A_b2   = (const float*)d_in[8];
    const float* B_w1   = (const float*)d_in[9];
    const float* B_b1   = (const float*)d_in[10];
    const float* B_g    = (const float*)d_in[11];
    const float* B_beta = (const float*)d_in[12];
    const float* B_w2   = (const float*)d_in[13];
    const float* B_b2   = (const float*)d_in[14];
    const float* base_w = (const float*)d_in[15];
    const float* base_b = (const float*)d_in[16];

    float* out = (float*)d_out;   // reference output dtype is float32

    mlp_kernel<<<2 * BS, 256, 0, stream>>>(a_emb, b_emb,
        A_w1, A_b1, A_g, A_beta, A_w2, A_b2,
        B_w1, B_b1, B_g, B_beta, B_w2, B_b2);

    assemble_kernel<<<4 * BS, 256, 0, stream>>>(base_w);

    conv_kernel<<<1024, 256, 0, stream>>>(X, base_b, out);
}